// Round 18
// baseline (177.974 us; speedup 1.0000x reference)
//
#include <hip/hip_runtime.h>
#include <hip/hip_fp16.h>
#include <math.h>

#define N_NODES 50000
#define E_EDGES 800000
#define ETOT    (E_EDGES + N_NODES)

// bucketed scatter params
#define BUCK_SHIFT 9
#define BUCK_SZ   (1 << BUCK_SHIFT)                               // 512
#define NBUCK ((N_NODES + BUCK_SZ - 1) >> BUCK_SHIFT)             // 98
#define BS_EPT 16
#define BS_THREADS 256
#define BS_EPB (BS_THREADS * BS_EPT)                              // 4096
#define BS_NBLK ((ETOT + BS_EPB - 1) / BS_EPB)                    // 208

// fixed-capacity bucket slots in tmp
#define CAP_SHIFT 14
#define CAP (1 << CAP_SHIFT)                                      // 16384

#define GEMM0_GRID ((N_NODES + 63) / 64)                          // 782
#define PACK_GRID (GEMM0_GRID + BS_NBLK)                          // 990
#define AGG_GRID ((N_NODES + 3) / 4)                              // 12500

// ---------------------------------------------------------------------------
// PACKED: gemm0 (blocks 0..781) || binscatter (blocks 782..989).
// (r17-verified) After this kernel, cur[bk] == bucket bk's edge count.
// ---------------------------------------------------------------------------
__global__ __launch_bounds__(256)
void gemm0_binscatter_kernel(const float* __restrict__ X,
                             const float* __restrict__ W,
                             const float* __restrict__ a_s,
                             const float* __restrict__ a_d,
                             __half* __restrict__ H16,
                             float* __restrict__ asrc,
                             float* __restrict__ adst,
                             const int* __restrict__ ei,
                             int* __restrict__ cur,
                             unsigned int* __restrict__ tmp)
{
    __shared__ float smem[128 * 64];   // 32 KB
    const int t = threadIdx.x;

    if (blockIdx.x < GEMM0_GRID) {
        constexpr int DIN = 128, DOUT = 64, COLG = 16;
        float* Wl = smem;
        for (int i = t; i < DIN * DOUT / 4; i += 256)
            ((float4*)Wl)[i] = ((const float4*)W)[i];
        __syncthreads();

        const int row0b = blockIdx.x * 64;
        const int tx = t % COLG;
        const int ty = t / COLG;
        const int r0 = ty * 4;
        const int c0 = tx * 4;

        const float* Xr[4];
#pragma unroll
        for (int i = 0; i < 4; ++i) {
            int gr = row0b + r0 + i;
            Xr[i] = X + (size_t)min(gr, N_NODES - 1) * DIN;
        }

        float acc[4][4] = {};
#pragma unroll 4
        for (int kk = 0; kk < DIN; kk += 4) {
            float a[4][4], w[4][4];
#pragma unroll
            for (int i = 0; i < 4; ++i)
                *(float4*)a[i] = *(const float4*)&Xr[i][kk];
#pragma unroll
            for (int j = 0; j < 4; ++j)
                *(float4*)w[j] = *(const float4*)&Wl[(kk + j) * DOUT + c0];
#pragma unroll
            for (int i = 0; i < 4; ++i)
#pragma unroll
                for (int j = 0; j < 4; ++j)
                    acc[i][j] = fmaf(a[i][0], w[0][j],
                                fmaf(a[i][1], w[1][j],
                                fmaf(a[i][2], w[2][j],
                                fmaf(a[i][3], w[3][j], acc[i][j]))));
        }

        float as4[4], ad4[4];
        *(float4*)as4 = *(const float4*)&a_s[c0];
        *(float4*)ad4 = *(const float4*)&a_d[c0];

#pragma unroll
        for (int i = 0; i < 4; ++i) {
            const int gr = row0b + r0 + i;
            float ps = acc[i][0] * as4[0] + acc[i][1] * as4[1] +
                       acc[i][2] * as4[2] + acc[i][3] * as4[3];
            float pd = acc[i][0] * ad4[0] + acc[i][1] * ad4[1] +
                       acc[i][2] * ad4[2] + acc[i][3] * ad4[3];
#pragma unroll
            for (int off = COLG / 2; off >= 1; off >>= 1) {
                ps += __shfl_xor(ps, off, 64);
                pd += __shfl_xor(pd, off, 64);
            }
            if (gr < N_NODES) {
                __half2 p01 = __floats2half2_rn(acc[i][0], acc[i][1]);
                __half2 p23 = __floats2half2_rn(acc[i][2], acc[i][3]);
                uint2 pk;
                pk.x = *(unsigned int*)&p01;
                pk.y = *(unsigned int*)&p23;
                *(uint2*)&H16[gr * DOUT + c0] = pk;
                if (tx == 0) { asrc[gr] = ps; adst[gr] = pd; }
            }
        }
    } else {
        int* lcnt  = (int*)smem;
        int* lbase = lcnt + 128;

        for (int i = t; i < NBUCK; i += 256) lcnt[i] = 0;
        __syncthreads();

        const int e0 = (blockIdx.x - GEMM0_GRID) * BS_EPB;
        unsigned int pk[BS_EPT];
        int rk[BS_EPT];
        int bk[BS_EPT];
#pragma unroll
        for (int k = 0; k < BS_EPT; ++k) {
            const int eid = e0 + k * BS_THREADS + t;
            bk[k] = -1;
            if (eid < ETOT) {
                int src, dst;
                if (eid < E_EDGES) { src = ei[eid]; dst = ei[E_EDGES + eid]; }
                else               { src = dst = eid - E_EDGES; }
                bk[k] = dst >> BUCK_SHIFT;
                pk[k] = ((unsigned int)dst << 16) | (unsigned int)src;
                rk[k] = atomicAdd(&lcnt[bk[k]], 1);
            }
        }
        __syncthreads();
        for (int i = t; i < NBUCK; i += 256)
            if (lcnt[i] > 0)
                lbase[i] = (i << CAP_SHIFT) + atomicAdd(&cur[i], lcnt[i]);
        __syncthreads();
#pragma unroll
        for (int k = 0; k < BS_EPT; ++k)
            if (bk[k] >= 0) tmp[lbase[bk[k]] + rk[k]] = pk[k];
    }
}

// ---------------------------------------------------------------------------
// bucket_sort (r17-verified): strided tmp -> packed csr_pk + offs.
// ---------------------------------------------------------------------------
__global__ __launch_bounds__(BUCK_SZ)
void bucket_sort_kernel(const unsigned int* __restrict__ tmp,
                        const int* __restrict__ cur,
                        unsigned int* __restrict__ csr_pk,
                        int* __restrict__ offs)
{
    __shared__ int lcnt[BUCK_SZ];
    __shared__ int loff[BUCK_SZ];
    __shared__ int lcur[BUCK_SZ];
    __shared__ int sbase;
    const int bk = blockIdx.x;
    const int t  = threadIdx.x;

    {
        const int v = (t < NBUCK) ? cur[t] : 0;
        lcnt[t] = v;
        __syncthreads();
        for (int off = 1; off < 128; off <<= 1) {
            int u = (t >= off && t < 128) ? lcnt[t - off] : 0;
            __syncthreads();
            if (t < 128) lcnt[t] += u;
            __syncthreads();
        }
        if (t == bk) sbase = lcnt[t] - v;
    }
    __syncthreads();
    const int base  = sbase;
    const int tbase = bk << CAP_SHIFT;
    const int cnt   = cur[bk];

    lcnt[t] = 0;
    __syncthreads();
    for (int i = t; i < cnt; i += BUCK_SZ)
        atomicAdd(&lcnt[(tmp[tbase + i] >> 16) & (BUCK_SZ - 1)], 1);
    __syncthreads();

    const int v = lcnt[t];
    loff[t] = v;
    __syncthreads();
    for (int off = 1; off < BUCK_SZ; off <<= 1) {
        int u = (t >= off) ? loff[t - off] : 0;
        __syncthreads();
        loff[t] += u;
        __syncthreads();
    }
    const int excl = loff[t] - v;

    const int g = (bk << BUCK_SHIFT) + t;
    if (g <= N_NODES) offs[g] = base + excl;

    lcur[t] = excl;
    __syncthreads();
    for (int i = t; i < cnt; i += BUCK_SZ) {
        const unsigned int pk = tmp[tbase + i];
        const int l = (pk >> 16) & (BUCK_SZ - 1);
        const int pos = atomicAdd(&lcur[l], 1);
        csr_pk[base + pos] = pk;
    }
}

// ---------------------------------------------------------------------------
// agg_gemm: node_agg v5 (4 nodes/block, relu) -> act in LDS -> tiny gemm
// (4 x DOUT_NEXT, W in LDS) + alpha epilogue + fp16 H write.
// Parallelism preserved: 12500 blocks, agg structure identical to v5.
// ---------------------------------------------------------------------------
template<int DOUT_NEXT>
__global__ __launch_bounds__(256)
void agg_gemm_kernel(const int* __restrict__ offs,
                     const unsigned int* __restrict__ csr_pk,
                     const float* __restrict__ asrc_p,
                     const float* __restrict__ adst_p,
                     const __half* __restrict__ H16_p,
                     const float* __restrict__ b_p,
                     const float* __restrict__ W,
                     const float* __restrict__ a_s,
                     const float* __restrict__ a_d,
                     __half* __restrict__ H16_n,
                     float* __restrict__ asrc_n,
                     float* __restrict__ adst_n)
{
    constexpr int DIN = 64;            // prev-layer width (both fused layers)
    constexpr int FL = 8, SLOTS = 8;
    __shared__ float Wl[DIN * DOUT_NEXT];   // 16 KB or 8 KB
    __shared__ float act[4][DIN];           // 1 KB

    const int t = threadIdx.x;
    const int wv   = t >> 6;
    const int lane = t & 63;
    const int fl   = lane % FL;
    const int slot = lane / FL;
    const int node = blockIdx.x * 4 + wv;

    // stage W for the gemm epilogue
    for (int i = t; i < DIN * DOUT_NEXT / 4; i += 256)
        ((float4*)Wl)[i] = ((const float4*)W)[i];

    // ---- agg phase (v5 structure) ----
    int beg = 0, end = 0;
    float adn = 0.f;
    if (node < N_NODES) {
        beg = offs[node];
        end = offs[node + 1];
        adn = adst_p[node];
    }
    const __half* __restrict__ Hf = H16_p + fl * 8;

    float s = 0.f;
    float acc[8] = {};

    int eid = beg + slot;
    bool valid = (eid < end);
    unsigned int pk = valid ? csr_pk[eid] : 0u;

    for (int cb = beg; cb < end; cb += SLOTS) {
        const int nid = cb + SLOTS + slot;
        const bool nvalid = (nid < end);
        const unsigned int npk = nvalid ? csr_pk[nid] : 0u;

        float p = 0.f;
        uint4 h = make_uint4(0u, 0u, 0u, 0u);
        if (valid) {
            const unsigned int src = pk & 0xffffu;
            float v = asrc_p[src] + adn;
            v = fmaxf(v, 0.2f * v);
            p = __expf(fminf(v, 80.f));
            h = *(const uint4*)(Hf + src * DIN);
        }
        const float2 f0 = __half22float2(*(const __half2*)&h.x);
        const float2 f1 = __half22float2(*(const __half2*)&h.y);
        const float2 f2 = __half22float2(*(const __half2*)&h.z);
        const float2 f3 = __half22float2(*(const __half2*)&h.w);
        s += p;
        acc[0] = fmaf(p, f0.x, acc[0]);
        acc[1] = fmaf(p, f0.y, acc[1]);
        acc[2] = fmaf(p, f1.x, acc[2]);
        acc[3] = fmaf(p, f1.y, acc[3]);
        acc[4] = fmaf(p, f2.x, acc[4]);
        acc[5] = fmaf(p, f2.y, acc[5]);
        acc[6] = fmaf(p, f3.x, acc[6]);
        acc[7] = fmaf(p, f3.y, acc[7]);
        valid = nvalid;
        pk = npk;
    }

#pragma unroll
    for (int off = FL; off < 64; off <<= 1) {
        s += __shfl_xor(s, off, 64);
#pragma unroll
        for (int j = 0; j < 8; ++j)
            acc[j] += __shfl_xor(acc[j], off, 64);
    }

    if (slot == 0) {
        float o[8];
        if (node < N_NODES) {
            const float inv = 1.f / s;
#pragma unroll
            for (int j = 0; j < 8; ++j)
                o[j] = fmaxf(acc[j] * inv + b_p[fl * 8 + j], 0.f);  // relu
        } else {
#pragma unroll
            for (int j = 0; j < 8; ++j) o[j] = 0.f;
        }
#pragma unroll
        for (int j = 0; j < 8; ++j) act[wv][fl * 8 + j] = o[j];
    }
    __syncthreads();

    // ---- gemm epilogue: row wv, col = lane ----
    const int c = lane;
    float h = 0.f;
    if (c < DOUT_NEXT) {
#pragma unroll 8
        for (int k = 0; k < DIN; ++k)
            h = fmaf(act[wv][k], Wl[k * DOUT_NEXT + c], h);
    }
    float ps = (c < DOUT_NEXT) ? h * a_s[c] : 0.f;
    float pd = (c < DOUT_NEXT) ? h * a_d[c] : 0.f;
#pragma unroll
    for (int off = 32; off >= 1; off >>= 1) {
        ps += __shfl_xor(ps, off, 64);
        pd += __shfl_xor(pd, off, 64);
    }
    if (node < N_NODES) {
        if (c < DOUT_NEXT) H16_n[node * DOUT_NEXT + c] = __float2half(h);
        if (lane == 0) { asrc_n[node] = ps; adst_n[node] = pd; }
    }
}

// ---------------------------------------------------------------------------
// node_agg v5 final layer (tanh), unchanged.
// ---------------------------------------------------------------------------
template<int DOUT, int ACT>
__global__ __launch_bounds__(256)
void node_agg_kernel(const int* __restrict__ offs,
                     const unsigned int* __restrict__ csr_pk,
                     const float* __restrict__ asrc,
                     const float* __restrict__ adst,
                     const __half* __restrict__ H16,
                     const float* __restrict__ b,
                     float* __restrict__ out)
{
    constexpr int FL    = DOUT / 8;
    constexpr int SLOTS = 64 / FL;
    const int wv   = threadIdx.x >> 6;
    const int lane = threadIdx.x & 63;
    const int fl   = lane % FL;
    const int slot = lane / FL;
    const int node = blockIdx.x * 4 + wv;
    if (node >= N_NODES) return;

    const int beg = offs[node];
    const int end = offs[node + 1];
    const float adn = adst[node];
    const __half* __restrict__ Hf = H16 + fl * 8;

    float s = 0.f;
    float acc[8] = {};

    int eid = beg + slot;
    bool valid = (eid < end);
    unsigned int pk = valid ? csr_pk[eid] : 0u;

    for (int cb = beg; cb < end; cb += SLOTS) {
        const int nid = cb + SLOTS + slot;
        const bool nvalid = (nid < end);
        const unsigned int npk = nvalid ? csr_pk[nid] : 0u;

        float p = 0.f;
        uint4 h = make_uint4(0u, 0u, 0u, 0u);
        if (valid) {
            const unsigned int src = pk & 0xffffu;
            float v = asrc[src] + adn;
            v = fmaxf(v, 0.2f * v);
            p = __expf(fminf(v, 80.f));
            h = *(const uint4*)(Hf + src * DOUT);
        }
        const float2 f0 = __half22float2(*(const __half2*)&h.x);
        const float2 f1 = __half22float2(*(const __half2*)&h.y);
        const float2 f2 = __half22float2(*(const __half2*)&h.z);
        const float2 f3 = __half22float2(*(const __half2*)&h.w);
        s += p;
        acc[0] = fmaf(p, f0.x, acc[0]);
        acc[1] = fmaf(p, f0.y, acc[1]);
        acc[2] = fmaf(p, f1.x, acc[2]);
        acc[3] = fmaf(p, f1.y, acc[3]);
        acc[4] = fmaf(p, f2.x, acc[4]);
        acc[5] = fmaf(p, f2.y, acc[5]);
        acc[6] = fmaf(p, f3.x, acc[6]);
        acc[7] = fmaf(p, f3.y, acc[7]);
        valid = nvalid;
        pk = npk;
    }

#pragma unroll
    for (int off = FL; off < 64; off <<= 1) {
        s += __shfl_xor(s, off, 64);
#pragma unroll
        for (int j = 0; j < 8; ++j)
            acc[j] += __shfl_xor(acc[j], off, 64);
    }

    if (slot == 0) {
        const float inv = 1.f / s;
        float o[8];
#pragma unroll
        for (int j = 0; j < 8; ++j) {
            float v = acc[j] * inv + b[fl * 8 + j];
            o[j] = (ACT == 0) ? fmaxf(v, 0.f) : tanhf(v);
        }
        *(float4*)&out[node * DOUT + fl * 8]     = *(float4*)&o[0];
        *(float4*)&out[node * DOUT + fl * 8 + 4] = *(float4*)&o[4];
    }
}

// ---------------------------------------------------------------------------

extern "C" void kernel_launch(void* const* d_in, const int* in_sizes, int n_in,
                              void* d_out, int out_size, void* d_ws, size_t ws_size,
                              hipStream_t stream)
{
    const float* x  = (const float*)d_in[0];
    const int*   ei = (const int*)d_in[1];
    const float* W0 = (const float*)d_in[2];
    const float* as0= (const float*)d_in[3];
    const float* ad0= (const float*)d_in[4];
    const float* b0 = (const float*)d_in[5];
    const float* W1 = (const float*)d_in[6];
    const float* as1= (const float*)d_in[7];
    const float* ad1= (const float*)d_in[8];
    const float* b1 = (const float*)d_in[9];
    const float* W2 = (const float*)d_in[10];
    const float* as2= (const float*)d_in[11];
    const float* ad2= (const float*)d_in[12];
    const float* b2 = (const float*)d_in[13];
    float* out = (float*)d_out;

    char* wsb = (char*)d_ws;
    auto take = [&](size_t bytes) {
        char* p = wsb;
        wsb += (bytes + 255) & ~size_t(255);
        return p;
    };
    __half* h16a   = (__half*)take(sizeof(__half) * N_NODES * 64);
    __half* h16b   = (__half*)take(sizeof(__half) * N_NODES * 64);
    float* asrc_a  = (float*)take(sizeof(float) * N_NODES);
    float* adst_a  = (float*)take(sizeof(float) * N_NODES);
    float* asrc_b  = (float*)take(sizeof(float) * N_NODES);
    float* adst_b  = (float*)take(sizeof(float) * N_NODES);
    int*   offs    = (int*)take(sizeof(int) * (N_NODES + 1));
    int*   cur     = (int*)take(sizeof(int) * NBUCK);
    unsigned int* tmp    = (unsigned int*)take(sizeof(unsigned int) * NBUCK * CAP);
    unsigned int* csr_pk = (unsigned int*)take(sizeof(unsigned int) * ETOT);

    hipMemsetAsync(cur, 0, sizeof(int) * NBUCK, stream);

    // gemm0 || binscatter (independent)
    gemm0_binscatter_kernel<<<PACK_GRID, 256, 0, stream>>>(
        x, W0, as0, ad0, h16a, asrc_a, adst_a, ei, cur, tmp);

    bucket_sort_kernel<<<NBUCK, BUCK_SZ, 0, stream>>>(tmp, cur, csr_pk, offs);

    // agg(layer0, relu) + gemm(W1) + alpha1  ->  h16b, alpha_b
    agg_gemm_kernel<64><<<AGG_GRID, 256, 0, stream>>>(
        offs, csr_pk, asrc_a, adst_a, h16a, b0,
        W1, as1, ad1, h16b, asrc_b, adst_b);

    // agg(layer1, relu) + gemm(W2) + alpha2  ->  h16a (32-wide), alpha_a
    agg_gemm_kernel<32><<<AGG_GRID, 256, 0, stream>>>(
        offs, csr_pk, asrc_b, adst_b, h16b, b1,
        W2, as2, ad2, h16a, asrc_a, adst_a);

    // final aggregation + tanh
    node_agg_kernel<32, 1><<<AGG_GRID, 256, 0, stream>>>(
        offs, csr_pk, asrc_a, adst_a, h16a, b2, out);
}

// Round 19
// 163.237 us; speedup vs baseline: 1.0903x; 1.0903x over previous
//
#include <hip/hip_runtime.h>
#include <hip/hip_fp16.h>
#include <math.h>

#define N_NODES 50000
#define E_EDGES 800000
#define ETOT    (E_EDGES + N_NODES)

// bucketed scatter params
#define BUCK_SHIFT 9
#define BUCK_SZ   (1 << BUCK_SHIFT)                               // 512
#define NBUCK ((N_NODES + BUCK_SZ - 1) >> BUCK_SHIFT)             // 98
#define BS_EPT 16
#define BS_THREADS 256
#define BS_EPB (BS_THREADS * BS_EPT)                              // 4096
#define BS_NBLK ((ETOT + BS_EPB - 1) / BS_EPB)                    // 208

// fixed-capacity bucket slots in tmp (mean count 8704, sd ~90)
#define CAP_SHIFT 14
#define CAP (1 << CAP_SHIFT)                                      // 16384

#define GEMM0_GRID ((N_NODES + 63) / 64)                          // 782
#define PACK_GRID (GEMM0_GRID + BS_NBLK)                          // 990

// ---------------------------------------------------------------------------
// PACKED: gemm0 (blocks 0..781) || binscatter (blocks 782..989).
// binscatter needs NO histogram: fixed-capacity slots, cur[] zeroed.
// After this kernel, cur[bk] == bucket bk's edge count. (r17-verified)
// ---------------------------------------------------------------------------
__global__ __launch_bounds__(256)
void gemm0_binscatter_kernel(const float* __restrict__ X,
                             const float* __restrict__ W,
                             const float* __restrict__ a_s,
                             const float* __restrict__ a_d,
                             __half* __restrict__ H16,
                             float* __restrict__ asrc,
                             float* __restrict__ adst,
                             const int* __restrict__ ei,
                             int* __restrict__ cur,
                             unsigned int* __restrict__ tmp)
{
    __shared__ float smem[128 * 64];   // 32 KB
    const int t = threadIdx.x;

    if (blockIdx.x < GEMM0_GRID) {
        // ---- gemm0 branch: DIN=128, DOUT=64, no X staging (r13-verified) ----
        constexpr int DIN = 128, DOUT = 64, COLG = 16;
        float* Wl = smem;
        for (int i = t; i < DIN * DOUT / 4; i += 256)
            ((float4*)Wl)[i] = ((const float4*)W)[i];
        __syncthreads();

        const int row0b = blockIdx.x * 64;
        const int tx = t % COLG;
        const int ty = t / COLG;
        const int r0 = ty * 4;
        const int c0 = tx * 4;

        const float* Xr[4];
#pragma unroll
        for (int i = 0; i < 4; ++i) {
            int gr = row0b + r0 + i;
            Xr[i] = X + (size_t)min(gr, N_NODES - 1) * DIN;
        }

        float acc[4][4] = {};
#pragma unroll 4
        for (int kk = 0; kk < DIN; kk += 4) {
            float a[4][4], w[4][4];
#pragma unroll
            for (int i = 0; i < 4; ++i)
                *(float4*)a[i] = *(const float4*)&Xr[i][kk];
#pragma unroll
            for (int j = 0; j < 4; ++j)
                *(float4*)w[j] = *(const float4*)&Wl[(kk + j) * DOUT + c0];
#pragma unroll
            for (int i = 0; i < 4; ++i)
#pragma unroll
                for (int j = 0; j < 4; ++j)
                    acc[i][j] = fmaf(a[i][0], w[0][j],
                                fmaf(a[i][1], w[1][j],
                                fmaf(a[i][2], w[2][j],
                                fmaf(a[i][3], w[3][j], acc[i][j]))));
        }

        float as4[4], ad4[4];
        *(float4*)as4 = *(const float4*)&a_s[c0];
        *(float4*)ad4 = *(const float4*)&a_d[c0];

#pragma unroll
        for (int i = 0; i < 4; ++i) {
            const int gr = row0b + r0 + i;
            float ps = acc[i][0] * as4[0] + acc[i][1] * as4[1] +
                       acc[i][2] * as4[2] + acc[i][3] * as4[3];
            float pd = acc[i][0] * ad4[0] + acc[i][1] * ad4[1] +
                       acc[i][2] * ad4[2] + acc[i][3] * ad4[3];
#pragma unroll
            for (int off = COLG / 2; off >= 1; off >>= 1) {
                ps += __shfl_xor(ps, off, 64);
                pd += __shfl_xor(pd, off, 64);
            }
            if (gr < N_NODES) {
                __half2 p01 = __floats2half2_rn(acc[i][0], acc[i][1]);
                __half2 p23 = __floats2half2_rn(acc[i][2], acc[i][3]);
                uint2 pk;
                pk.x = *(unsigned int*)&p01;
                pk.y = *(unsigned int*)&p23;
                *(uint2*)&H16[gr * DOUT + c0] = pk;
                if (tx == 0) { asrc[gr] = ps; adst[gr] = pd; }
            }
        }
    } else {
        // ---- binscatter branch: fixed-capacity slots, no scan needed ----
        int* lcnt  = (int*)smem;           // [NBUCK]
        int* lbase = lcnt + 128;           // [NBUCK]

        for (int i = t; i < NBUCK; i += 256) lcnt[i] = 0;
        __syncthreads();

        const int e0 = (blockIdx.x - GEMM0_GRID) * BS_EPB;
        unsigned int pk[BS_EPT];
        int rk[BS_EPT];
        int bk[BS_EPT];
#pragma unroll
        for (int k = 0; k < BS_EPT; ++k) {
            const int eid = e0 + k * BS_THREADS + t;
            bk[k] = -1;
            if (eid < ETOT) {
                int src, dst;
                if (eid < E_EDGES) { src = ei[eid]; dst = ei[E_EDGES + eid]; }
                else               { src = dst = eid - E_EDGES; }
                bk[k] = dst >> BUCK_SHIFT;
                pk[k] = ((unsigned int)dst << 16) | (unsigned int)src;
                rk[k] = atomicAdd(&lcnt[bk[k]], 1);
            }
        }
        __syncthreads();
        for (int i = t; i < NBUCK; i += 256)
            if (lcnt[i] > 0)
                lbase[i] = (i << CAP_SHIFT) + atomicAdd(&cur[i], lcnt[i]);
        __syncthreads();
#pragma unroll
        for (int k = 0; k < BS_EPT; ++k)
            if (bk[k] >= 0) tmp[lbase[bk[k]] + rk[k]] = pk[k];
    }
}

// ---------------------------------------------------------------------------
// bucket_sort: reads tmp at fixed-stride base, counts from cur (filled by
// binscatter), csr base via local scan of cur. Emits csr_pk + offs.
// (r17-verified)
// ---------------------------------------------------------------------------
__global__ __launch_bounds__(BUCK_SZ)
void bucket_sort_kernel(const unsigned int* __restrict__ tmp,
                        const int* __restrict__ cur,
                        unsigned int* __restrict__ csr_pk,
                        int* __restrict__ offs)
{
    __shared__ int lcnt[BUCK_SZ];
    __shared__ int loff[BUCK_SZ];
    __shared__ int lcur[BUCK_SZ];
    __shared__ int sbase;
    const int bk = blockIdx.x;
    const int t  = threadIdx.x;

    // csr base = exclusive prefix of cur[] at bk (local 128-wide scan)
    {
        const int v = (t < NBUCK) ? cur[t] : 0;
        lcnt[t] = v;
        __syncthreads();
        for (int off = 1; off < 128; off <<= 1) {
            int u = (t >= off && t < 128) ? lcnt[t - off] : 0;
            __syncthreads();
            if (t < 128) lcnt[t] += u;
            __syncthreads();
        }
        if (t == bk) sbase = lcnt[t] - v;
    }
    __syncthreads();
    const int base  = sbase;                 // csr base
    const int tbase = bk << CAP_SHIFT;       // tmp base
    const int cnt   = cur[bk];

    lcnt[t] = 0;
    __syncthreads();
    for (int i = t; i < cnt; i += BUCK_SZ)
        atomicAdd(&lcnt[(tmp[tbase + i] >> 16) & (BUCK_SZ - 1)], 1);
    __syncthreads();

    const int v = lcnt[t];
    loff[t] = v;
    __syncthreads();
    for (int off = 1; off < BUCK_SZ; off <<= 1) {
        int u = (t >= off) ? loff[t - off] : 0;
        __syncthreads();
        loff[t] += u;
        __syncthreads();
    }
    const int excl = loff[t] - v;

    const int g = (bk << BUCK_SHIFT) + t;
    if (g <= N_NODES) offs[g] = base + excl;   // tail node writes offs[N]=ETOT

    lcur[t] = excl;
    __syncthreads();
    for (int i = t; i < cnt; i += BUCK_SZ) {
        const unsigned int pk = tmp[tbase + i];
        const int l = (pk >> 16) & (BUCK_SZ - 1);
        const int pos = atomicAdd(&lcur[l], 1);
        csr_pk[base + pos] = pk;
    }
}

// ---------------------------------------------------------------------------
// Generic GEMM + alpha (layers 1,2) — no X staging, W in LDS (r13-verified).
// ---------------------------------------------------------------------------
template<int DIN, int DOUT>
__global__ __launch_bounds__(256)
void gemm_alpha_kernel(const float* __restrict__ X, const float* __restrict__ W,
                       const float* __restrict__ a_s, const float* __restrict__ a_d,
                       __half* __restrict__ H16, float* __restrict__ asrc,
                       float* __restrict__ adst)
{
    constexpr int COLG = DOUT / 4;
    constexpr int ROWG = 256 / COLG;
    constexpr int BM   = ROWG * 4;

    __shared__ float Wl[DIN * DOUT];

    const int tid = threadIdx.x;
    const int row0b = blockIdx.x * BM;

    for (int i = tid; i < DIN * DOUT / 4; i += 256)
        ((float4*)Wl)[i] = ((const float4*)W)[i];
    __syncthreads();

    const int tx = tid % COLG;
    const int ty = tid / COLG;
    const int r0 = ty * 4;
    const int c0 = tx * 4;

    const float* Xr[4];
#pragma unroll
    for (int i = 0; i < 4; ++i) {
        int gr = row0b + r0 + i;
        Xr[i] = X + (size_t)min(gr, N_NODES - 1) * DIN;
    }

    float acc[4][4] = {};
#pragma unroll 4
    for (int kk = 0; kk < DIN; kk += 4) {
        float a[4][4], w[4][4];
#pragma unroll
        for (int i = 0; i < 4; ++i)
            *(float4*)a[i] = *(const float4*)&Xr[i][kk];
#pragma unroll
        for (int j = 0; j < 4; ++j)
            *(float4*)w[j] = *(const float4*)&Wl[(kk + j) * DOUT + c0];
#pragma unroll
        for (int i = 0; i < 4; ++i)
#pragma unroll
            for (int j = 0; j < 4; ++j)
                acc[i][j] = fmaf(a[i][0], w[0][j],
                            fmaf(a[i][1], w[1][j],
                            fmaf(a[i][2], w[2][j],
                            fmaf(a[i][3], w[3][j], acc[i][j]))));
    }

    float as4[4], ad4[4];
    *(float4*)as4 = *(const float4*)&a_s[c0];
    *(float4*)ad4 = *(const float4*)&a_d[c0];

#pragma unroll
    for (int i = 0; i < 4; ++i) {
        const int gr = row0b + r0 + i;
        float ps = acc[i][0] * as4[0] + acc[i][1] * as4[1] +
                   acc[i][2] * as4[2] + acc[i][3] * as4[3];
        float pd = acc[i][0] * ad4[0] + acc[i][1] * ad4[1] +
                   acc[i][2] * ad4[2] + acc[i][3] * ad4[3];
#pragma unroll
        for (int off = COLG / 2; off >= 1; off >>= 1) {
            ps += __shfl_xor(ps, off, 64);
            pd += __shfl_xor(pd, off, 64);
        }
        if (gr < N_NODES) {
            __half2 p01 = __floats2half2_rn(acc[i][0], acc[i][1]);
            __half2 p23 = __floats2half2_rn(acc[i][2], acc[i][3]);
            uint2 pk;
            pk.x = *(unsigned int*)&p01;
            pk.y = *(unsigned int*)&p23;
            *(uint2*)&H16[gr * DOUT + c0] = pk;
            if (tx == 0) { asrc[gr] = ps; adst[gr] = pd; }
        }
    }
}

// ---------------------------------------------------------------------------
// node_agg v5 (verified): inline score, 16B fp16 gathers, pk prefetch.
// ---------------------------------------------------------------------------
template<int DOUT, int ACT>
__global__ __launch_bounds__(256)
void node_agg_kernel(const int* __restrict__ offs,
                     const unsigned int* __restrict__ csr_pk,
                     const float* __restrict__ asrc,
                     const float* __restrict__ adst,
                     const __half* __restrict__ H16,
                     const float* __restrict__ b,
                     float* __restrict__ out)
{
    constexpr int FL    = DOUT / 8;    // 8 (dout=64) or 4 (dout=32)
    constexpr int SLOTS = 64 / FL;     // 8 or 16
    const int wv   = threadIdx.x >> 6;
    const int lane = threadIdx.x & 63;
    const int fl   = lane % FL;
    const int slot = lane / FL;
    const int node = blockIdx.x * 4 + wv;
    if (node >= N_NODES) return;

    const int beg = offs[node];
    const int end = offs[node + 1];
    const float adn = adst[node];
    const __half* __restrict__ Hf = H16 + fl * 8;

    float s = 0.f;
    float acc[8] = {};

    int eid = beg + slot;
    bool valid = (eid < end);
    unsigned int pk = valid ? csr_pk[eid] : 0u;

    for (int cb = beg; cb < end; cb += SLOTS) {
        const int nid = cb + SLOTS + slot;
        const bool nvalid = (nid < end);
        const unsigned int npk = nvalid ? csr_pk[nid] : 0u;

        float p = 0.f;
        uint4 h = make_uint4(0u, 0u, 0u, 0u);
        if (valid) {
            const unsigned int src = pk & 0xffffu;
            float v = asrc[src] + adn;
            v = fmaxf(v, 0.2f * v);
            p = __expf(fminf(v, 80.f));
            h = *(const uint4*)(Hf + src * DOUT);
        }
        const float2 f0 = __half22float2(*(const __half2*)&h.x);
        const float2 f1 = __half22float2(*(const __half2*)&h.y);
        const float2 f2 = __half22float2(*(const __half2*)&h.z);
        const float2 f3 = __half22float2(*(const __half2*)&h.w);
        s += p;
        acc[0] = fmaf(p, f0.x, acc[0]);
        acc[1] = fmaf(p, f0.y, acc[1]);
        acc[2] = fmaf(p, f1.x, acc[2]);
        acc[3] = fmaf(p, f1.y, acc[3]);
        acc[4] = fmaf(p, f2.x, acc[4]);
        acc[5] = fmaf(p, f2.y, acc[5]);
        acc[6] = fmaf(p, f3.x, acc[6]);
        acc[7] = fmaf(p, f3.y, acc[7]);
        valid = nvalid;
        pk = npk;
    }

#pragma unroll
    for (int off = FL; off < 64; off <<= 1) {
        s += __shfl_xor(s, off, 64);
#pragma unroll
        for (int j = 0; j < 8; ++j)
            acc[j] += __shfl_xor(acc[j], off, 64);
    }

    if (slot == 0) {
        const float inv = 1.f / s;
        float o[8];
#pragma unroll
        for (int j = 0; j < 8; ++j) {
            float v = acc[j] * inv + b[fl * 8 + j];
            o[j] = (ACT == 0) ? fmaxf(v, 0.f) : tanhf(v);
        }
        *(float4*)&out[node * DOUT + fl * 8]     = *(float4*)&o[0];
        *(float4*)&out[node * DOUT + fl * 8 + 4] = *(float4*)&o[4];
    }
}

// ---------------------------------------------------------------------------

extern "C" void kernel_launch(void* const* d_in, const int* in_sizes, int n_in,
                              void* d_out, int out_size, void* d_ws, size_t ws_size,
                              hipStream_t stream)
{
    const float* x  = (const float*)d_in[0];
    const int*   ei = (const int*)d_in[1];
    const float* W0 = (const float*)d_in[2];
    const float* as0= (const float*)d_in[3];
    const float* ad0= (const float*)d_in[4];
    const float* b0 = (const float*)d_in[5];
    const float* W1 = (const float*)d_in[6];
    const float* as1= (const float*)d_in[7];
    const float* ad1= (const float*)d_in[8];
    const float* b1 = (const float*)d_in[9];
    const float* W2 = (const float*)d_in[10];
    const float* as2= (const float*)d_in[11];
    const float* ad2= (const float*)d_in[12];
    const float* b2 = (const float*)d_in[13];
    float* out = (float*)d_out;

    char* wsb = (char*)d_ws;
    auto take = [&](size_t bytes) {
        char* p = wsb;
        wsb += (bytes + 255) & ~size_t(255);
        return p;
    };
    __half* h16    = (__half*)take(sizeof(__half) * N_NODES * 64);
    float* buf_act = (float*)take(sizeof(float) * N_NODES * 64);
    float* asrc    = (float*)take(sizeof(float) * N_NODES);
    float* adst    = (float*)take(sizeof(float) * N_NODES);
    int*   offs    = (int*)take(sizeof(int) * (N_NODES + 1));
    int*   cur     = (int*)take(sizeof(int) * NBUCK);
    unsigned int* tmp    = (unsigned int*)take(sizeof(unsigned int) * NBUCK * CAP);
    unsigned int* csr_pk = (unsigned int*)take(sizeof(unsigned int) * ETOT);

    hipMemsetAsync(cur, 0, sizeof(int) * NBUCK, stream);

    // gemm0 and binscatter are independent -> one packed dispatch
    gemm0_binscatter_kernel<<<PACK_GRID, 256, 0, stream>>>(
        x, W0, as0, ad0, h16, asrc, adst, ei, cur, tmp);

    bucket_sort_kernel<<<NBUCK, BUCK_SZ, 0, stream>>>(tmp, cur, csr_pk, offs);

    const int agg_grid = (N_NODES + 3) / 4;
    node_agg_kernel<64, 0><<<agg_grid, 256, 0, stream>>>(
        offs, csr_pk, asrc, adst, h16, b0, buf_act);

    gemm_alpha_kernel<64, 64><<<GEMM0_GRID, 256, 0, stream>>>(
        buf_act, W1, as1, ad1, h16, asrc, adst);
    node_agg_kernel<64, 0><<<agg_grid, 256, 0, stream>>>(
        offs, csr_pk, asrc, adst, h16, b1, buf_act);

    gemm_alpha_kernel<64, 32><<<(N_NODES + 127) / 128, 256, 0, stream>>>(
        buf_act, W2, as2, ad2, h16, asrc, adst);
    node_agg_kernel<32, 1><<<agg_grid, 256, 0, stream>>>(
        offs, csr_pk, asrc, adst, h16, b2, out);
}